// Round 8
// baseline (2630.727 us; speedup 1.0000x reference)
//
#include <hip/hip_runtime.h>
#include <math.h>

#define G_    1024
#define NPG   126
#define EPG   450
#define NN    (G_*NPG)      // 129024
#define EE    (G_*EPG)      // 460800
#define F_    126
#define EPSV  1e-5f

#define KS_POST 20                    // 4 (h, K=128) + 16 (vstat, K=512)
#define SEGB_SZ (KS_POST*8*64*8)      // 81920 shorts per (layer,seg)
#define SMALLB_SZ (4*8*64*8)          // 16384 shorts per 128x128 matrix

typedef unsigned short u16;
typedef unsigned int   u32;
typedef __attribute__((ext_vector_type(8))) short bf8v;   // 8 bf16 in 4 VGPRs
typedef __attribute__((ext_vector_type(4))) float f4v;

union U4 { bf8v v; u32 a[4]; };

__device__ __forceinline__ u16 f2b(float f) {              // RNE f32 -> bf16
    u32 u = __float_as_uint(f);
    u += 0x7FFFu + ((u >> 16) & 1u);
    return (u16)(u >> 16);
}
__device__ __forceinline__ float b2f(u16 s) { return __uint_as_float(((u32)s) << 16); }
__device__ __forceinline__ float b2f_lo(u32 u) { return __uint_as_float(u << 16); }
__device__ __forceinline__ float b2f_hi(u32 u) { return __uint_as_float(u & 0xFFFF0000u); }

// ---------------- node embedding: hb = bf16(x @ emb1_w + emb1_b), short8 stores ----------
__global__ void k_embed(const float* __restrict__ x, const float* __restrict__ w,
                        const float* __restrict__ b, u16* __restrict__ hb) {
    int idx = (blockIdx.x * 256 + threadIdx.x) * 8;
    if (idx >= NN * 128) return;
    int n = idx >> 7, f0 = idx & 127;
    float xr[5];
#pragma unroll
    for (int c = 0; c < 5; ++c) xr[c] = x[n * 5 + c];
    float v[8];
#pragma unroll
    for (int j = 0; j < 8; ++j) {
        int f = f0 + j;
        float s = 0.f;
        if (f < F_) {
            s = b[f];
#pragma unroll
            for (int c = 0; c < 5; ++c) s += xr[c] * w[c * F_ + f];
        }
        v[j] = s;
    }
    U4 o;
#pragma unroll
    for (int i = 0; i < 4; ++i) o.a[i] = (u32)f2b(v[2 * i]) | ((u32)f2b(v[2 * i + 1]) << 16);
    *(bf8v*)(hb + idx) = o.v;
}

// ---------------- per-graph CSR build: epack = src_local | attr<<8 ----------------
__global__ void k_build_csr(const int* __restrict__ src, const int* __restrict__ dst,
                            const int* __restrict__ attr,
                            int* __restrict__ deg, int* __restrict__ rstart,
                            int* __restrict__ epack) {
    int g = blockIdx.x;
    __shared__ int scnt[NPG];
    __shared__ int spos[NPG];
    int t = threadIdx.x;
    for (int j = t; j < NPG; j += blockDim.x) scnt[j] = 0;
    __syncthreads();
    int e0 = g * EPG;
    for (int i = t; i < EPG; i += blockDim.x) {
        int dl = dst[e0 + i] - g * NPG;
        atomicAdd(&scnt[dl], 1);
    }
    __syncthreads();
    if (t == 0) {
        int run = 0;
        for (int j = 0; j < NPG; ++j) { spos[j] = run; run += scnt[j]; }
    }
    __syncthreads();
    for (int j = t; j < NPG; j += blockDim.x) {
        deg[g * NPG + j]    = scnt[j];
        rstart[g * NPG + j] = e0 + spos[j];
    }
    __syncthreads();
    for (int j = t; j < NPG; j += blockDim.x) scnt[j] = 0;
    __syncthreads();
    for (int i = t; i < EPG; i += blockDim.x) {
        int e  = e0 + i;
        int dl = dst[e] - g * NPG;
        int p  = atomicAdd(&scnt[dl], 1);
        epack[e0 + spos[dl] + p] = (src[e] - g * NPG) | (attr[e] << 8);  // local src <126
    }
}

// ---------------- edge-attr table (fp32): etab[(l*10+a)*F_ + f] ----------------
__global__ void k_build_etab(const float* __restrict__ edge_tab, const float* __restrict__ enc_w,
                             const float* __restrict__ enc_b, const float* __restrict__ pre_w,
                             const float* __restrict__ pre_b, float* __restrict__ etab) {
    int l = blockIdx.x / 10, a = blockIdx.x % 10;
    __shared__ float tmp[F_];
    int t = threadIdx.x;
    if (t < F_) {
        float s = enc_b[l * F_ + t];
        for (int c = 0; c < 50; ++c) s += edge_tab[a * 50 + c] * enc_w[(l * 50 + c) * F_ + t];
        tmp[t] = s;
    }
    __syncthreads();
    if (t < F_) {
        float s = pre_b[l * F_ + t];
        for (int j = 0; j < F_; ++j) s += tmp[j] * pre_w[((size_t)l * 378 + 252 + j) * F_ + t];
        etab[(l * 10 + a) * F_ + t] = s;
    }
}

// ------------- fold: T[l][seg][k][c] = (seg==0? B0 : 0) + sum_f Wi[k][f]*Bsum_seg[f][c] -----
// Bsum_seg[f][c] = sum_{t=mean,min,max} post_w[l][126 + seg*504 + t*126 + f][c]
__global__ void k_fold_T(const float* __restrict__ pre_w, const float* __restrict__ post_w,
                         float* __restrict__ Tbuf) {
    int k = blockIdx.x;                 // 0..127
    int y = blockIdx.y;                 // l*3+seg
    int l = y / 3, seg = y % 3;
    int c = threadIdx.x;                // 0..127
    __shared__ float wi[128];
    wi[c] = (k < F_ && c < F_) ? pre_w[((size_t)l * 378 + k) * F_ + c] : 0.f;
    __syncthreads();
    float s = 0.f;
    if (k < F_ && c < F_) {
        const float* pw = post_w + (size_t)l * 1638 * F_;
        if (seg == 0) s = pw[(size_t)k * F_ + c];
        int base = 126 + seg * 504;
        for (int f = 0; f < F_; ++f) {
            float bs = pw[(size_t)(base + f) * F_ + c]
                     + pw[(size_t)(base + 126 + f) * F_ + c]
                     + pw[(size_t)(base + 252 + f) * F_ + c];
            s += wi[f] * bs;
        }
    }
    Tbuf[((size_t)y * 128 + k) * 128 + c] = s;
}

// ------------- Wc[l][k][c] = -((T1-B0) + amp0*T2 + att0*T3)  (deg==0 correction weights) ----
__global__ void k_fold_Wc(const float* __restrict__ Tbuf, const float* __restrict__ post_w,
                          const int* __restrict__ deg_hist, float* __restrict__ WcBuf) {
    int idx = blockIdx.x * 256 + threadIdx.x;
    if (idx >= 4 * 128 * 128) return;
    int l = idx >> 14, k = (idx >> 7) & 127, c = idx & 127;
    float dsum = 0.f, dsl = 0.f;
#pragma unroll
    for (int b = 0; b < 5; ++b) {
        float dh = (float)deg_hist[b];
        dsum += dh; dsl += dh * logf((float)b + 1.f);
    }
    float avgl = dsl / dsum;
    float l2 = logf(2.f);
    float amp0 = l2 / avgl, att0 = avgl / l2;
    float t1 = Tbuf[((size_t)(l * 3 + 0) * 128 + k) * 128 + c];
    float t2 = Tbuf[((size_t)(l * 3 + 1) * 128 + k) * 128 + c];
    float t3 = Tbuf[((size_t)(l * 3 + 2) * 128 + k) * 128 + c];
    float b0 = (k < F_ && c < F_) ? post_w[((size_t)l * 1638 + k) * F_ + c] : 0.f;
    WcBuf[((size_t)l * 128 + k) * 128 + c] = -((t1 - b0) + amp0 * t2 + att0 * t3);
}

// ---------------- B prep (128x128): frag-linear bf16 ----------------
// out[((ks*8+pnl)*64+lane)*8+j] = B[ks*32+(lane>>4)*8+j][pnl*16+(lane&15)]
__global__ void k_prep_B128(const float* __restrict__ pre_w, const float* __restrict__ lin_w,
                            const float* __restrict__ WcBuf,
                            u16* __restrict__ wjB, u16* __restrict__ linB,
                            u16* __restrict__ wcB) {
    int idx = blockIdx.x * 256 + threadIdx.x;        // 0..16383
    int y = blockIdx.y;                              // 0..11
    int l = y & 3, ty = y >> 2;
    int j = idx & 7, lane = (idx >> 3) & 63, pnl = (idx >> 9) & 7, ks = idx >> 12;
    int k = ks * 32 + (lane >> 4) * 8 + j;
    int c = pnl * 16 + (lane & 15);
    float v;
    if (ty == 2) {
        v = WcBuf[((size_t)l * 128 + k) * 128 + c];
    } else {
        const float* W = (ty == 0) ? pre_w + ((size_t)l * 378 + 126) * F_
                                   : lin_w + (size_t)l * F_ * F_;
        v = (k < F_ && c < F_) ? W[(size_t)k * F_ + c] : 0.f;
    }
    u16* out = ((ty == 0) ? wjB : (ty == 1) ? linB : wcB) + (size_t)l * SMALLB_SZ;
    out[idx] = f2b(v);
}

// post B per (l,seg): ks<4 -> T rows; ks>=4 -> interleaved vstat rows a=f*4+t
__global__ void k_prep_Bpost(const float* __restrict__ post_w, const float* __restrict__ Tbuf,
                             u16* __restrict__ postB) {
    int idx = blockIdx.x * 256 + threadIdx.x;
    if (idx >= SEGB_SZ) return;
    int y = blockIdx.y;                 // l*3+seg
    int l = y / 3, seg = y % 3;
    int j = idx & 7, lane = (idx >> 3) & 63, pnl = (idx >> 9) & 7, ks = idx >> 12;
    int c  = pnl * 16 + (lane & 15);
    int kk = (lane >> 4) * 8 + j;       // 0..31
    float val = 0.f;
    if (ks < 4) {
        int k = ks * 32 + kk;           // 0..127 (T zero-padded)
        val = Tbuf[((size_t)y * 128 + k) * 128 + c];
    } else {
        int kv = (ks - 4) * 32 + kk;    // 0..511
        int f = kv >> 2, t = kv & 3;    // t: 0 mean, 1 min, 2 max, 3 std
        if (f < F_ && c < F_)
            val = post_w[((size_t)l * 1638 + 126 + seg * 504 + t * 126 + f) * F_ + c];
    }
    postB[(size_t)y * SEGB_SZ + idx] = f2b(val);
}

// ---------------- small MFMA GEMM (K=128), dual via grid.y, optional fused BN stats --------
template<int OF32, int BNSTAT>
__global__ __launch_bounds__(256) void k_gemm_mfma(
        const u16* __restrict__ A0,
        const u16* __restrict__ Bv0, const u16* __restrict__ Bv1,
        const float* __restrict__ bias0, const float* __restrict__ bias1,
        void* __restrict__ C0, void* __restrict__ C1,
        float* __restrict__ bns) {
    const u16* Bv = blockIdx.y ? Bv1 : Bv0;
    const float* bias = blockIdx.y ? bias1 : bias0;
    void* C = blockIdx.y ? C1 : C0;
    __shared__ float ldsS[128];
    __shared__ float ldsQ[128];
    int tid = threadIdx.x;
    if (BNSTAT) {
        if (tid < 128) { ldsS[tid] = 0.f; ldsQ[tid] = 0.f; }
        __syncthreads();
    }
    int lane = tid & 63, wid = tid >> 6;
    int g = lane >> 4, r15 = lane & 15;
    int wr = (wid >> 1) * 32, wc = (wid & 1) * 64;
    size_t row0 = (size_t)blockIdx.x * 64 + wr + r15;
    const u16* a0p = A0 + row0 * 128 + g * 8;
    const u16* a1p = a0p + 16 * 128;
    const u16* bp = Bv + ((size_t)(wc >> 4) * 64 + lane) * 8;
    f4v acc[2][4];
#pragma unroll
    for (int i = 0; i < 2; ++i)
#pragma unroll
        for (int j = 0; j < 4; ++j) acc[i][j] = (f4v){0.f, 0.f, 0.f, 0.f};

#pragma unroll
    for (int ks = 0; ks < 4; ++ks) {
        bf8v a0 = *(const bf8v*)(a0p + ks * 32);
        bf8v a1 = *(const bf8v*)(a1p + ks * 32);
        const u16* bk = bp + (size_t)ks * 4096;
#pragma unroll
        for (int fc = 0; fc < 4; ++fc) {
            bf8v bb = *(const bf8v*)(bk + fc * 512);
            acc[0][fc] = __builtin_amdgcn_mfma_f32_16x16x32_bf16(a0, bb, acc[0][fc], 0, 0, 0);
            acc[1][fc] = __builtin_amdgcn_mfma_f32_16x16x32_bf16(a1, bb, acc[1][fc], 0, 0, 0);
        }
    }
    int erow = blockIdx.x * 64 + wr + g * 4;
    int ecol = wc + r15;
#pragma unroll
    for (int fc = 0; fc < 4; ++fc) {
        int col = ecol + fc * 16;
        float bv = (bias && col < F_) ? bias[col] : 0.f;
        float s = 0.f, q = 0.f;
#pragma unroll
        for (int fr = 0; fr < 2; ++fr) {
#pragma unroll
            for (int r = 0; r < 4; ++r) {
                int row = erow + fr * 16 + r;
                float val = acc[fr][fc][r] + bv;
                if (BNSTAT) { s += val; q += val * val; }
                if (OF32) {
                    if (col < F_) ((float*)C)[(size_t)row * 128 + col] = val;
                } else {
                    ((u16*)C)[(size_t)row * 128 + col] = (col < F_) ? f2b(val) : (u16)0;
                }
            }
        }
        if (BNSTAT) { atomicAdd(&ldsS[col], s); atomicAdd(&ldsQ[col], q); }
    }
    if (BNSTAT) {
        __syncthreads();
        if (tid < 128) {
            atomicAdd(&bns[tid], ldsS[tid]);
            atomicAdd(&bns[128 + tid], ldsQ[tid]);
        }
    }
}

// ---------------- v-stat A-fragment: [mean,min,max,std](f0), [..](f0+1) as 8 bf16 -----------
__device__ __forceinline__ bf8v vstat_frag(const u32* __restrict__ PsL,
                                           const float* __restrict__ etL,
                                           const u32* __restrict__ epL,
                                           int dg, int rl, int f0) {
    float m0, n0, x0, d0, m1, n1, x1, d1;
    if (dg == 0 || f0 >= F_) {
        m0 = n0 = x0 = 0.f; m1 = n1 = x1 = 0.f;
        d0 = d1 = 0.0031622776601683794f;   // sqrt(1e-5)
    } else {
        float s0 = 0.f, q0 = 0.f, s1 = 0.f, q1 = 0.f;
        n0 = 3.4e38f; x0 = -3.4e38f; n1 = 3.4e38f; x1 = -3.4e38f;
        int ho = f0 >> 1;
        for (int e = 0; e < dg; ++e) {
            u32 pk = epL[rl + e];
            int sN = pk & 255, at = pk >> 8;
            u32 pv = PsL[sN * 65 + ho];
            float v0 = b2f_lo(pv) + etL[at * 130 + f0];
            float v1 = b2f_hi(pv) + etL[at * 130 + f0 + 1];
            s0 += v0; q0 += v0 * v0; n0 = fminf(n0, v0); x0 = fmaxf(x0, v0);
            s1 += v1; q1 += v1 * v1; n1 = fminf(n1, v1); x1 = fmaxf(x1, v1);
        }
        float ic = 1.f / (float)dg;
        m0 = s0 * ic; m1 = s1 * ic;
        d0 = sqrtf(fmaxf(q0 * ic - m0 * m0, 0.f) + EPSV);
        d1 = sqrtf(fmaxf(q1 * ic - m1 * m1, 0.f) + EPSV);
    }
    U4 o;
    o.a[0] = (u32)f2b(m0) | ((u32)f2b(n0) << 16);
    o.a[1] = (u32)f2b(x0) | ((u32)f2b(d0) << 16);
    o.a[2] = (u32)f2b(m1) | ((u32)f2b(n1) << 16);
    o.a[3] = (u32)f2b(x1) | ((u32)f2b(d1) << 16);
    return o.v;
}

// ---------------- fused per-graph post kernel -----------------------------------------------
// out = [h | vstat] @ (T1;B1) + amp*([h|vstat]@(T2;B2)) + att*(...) + bias (+corr if deg==0)
__global__ __launch_bounds__(256, 1) void k_post_fused(
        const u16* __restrict__ hb, const u16* __restrict__ Ps,
        const u16* __restrict__ corr,
        const float* __restrict__ etab_l,
        const int* __restrict__ deg, const int* __restrict__ rstart,
        const int* __restrict__ epack,
        const u16* __restrict__ postB_l, const float* __restrict__ bias,
        const int* __restrict__ deg_hist,
        u16* __restrict__ outC) {
    __shared__ u32  PsL[126 * 65];      // pad-65 stride: conflict-free random-row reads
    __shared__ float etL[10 * 130];
    __shared__ u32  epL[EPG];
    __shared__ int  degL[128];
    __shared__ int  rlocL[128];
    int g = blockIdx.x;
    int tid = threadIdx.x;
    float dsum = 0.f, dsl = 0.f;
#pragma unroll
    for (int b = 0; b < 5; ++b) {
        float dh = (float)deg_hist[b];
        dsum += dh; dsl += dh * logf((float)b + 1.f);
    }
    float avgl = dsl / dsum;
    // phase 0: stage graph data
    const u16* psrow = Ps + (size_t)g * NPG * 128;
    for (int i = tid; i < NPG * 16; i += 256) {
        int r = i >> 4, q = i & 15;
        U4 u; u.v = *(const bf8v*)(psrow + r * 128 + q * 8);
        u32* dp = &PsL[r * 65 + q * 4];
        dp[0] = u.a[0]; dp[1] = u.a[1]; dp[2] = u.a[2]; dp[3] = u.a[3];
    }
    for (int i = tid; i < 1280; i += 256) {
        int a = i >> 7, f = i & 127;
        etL[a * 130 + f] = (f < F_) ? etab_l[a * F_ + f] : 0.f;
    }
    for (int e = tid; e < EPG; e += 256) epL[e] = (u32)epack[(size_t)g * EPG + e];
    if (tid < 128) {
        degL[tid]  = (tid < NPG) ? deg[g * NPG + tid] : 0;
        rlocL[tid] = (tid < NPG) ? (rstart[g * NPG + tid] - g * EPG) : 0;
    }
    __syncthreads();

    int lane = tid & 63, wid = tid >> 6;
    int gq = lane >> 4, r15 = lane & 15;
    int wr = wid * 32;
    f4v acc[3][2][8];
#pragma unroll
    for (int s = 0; s < 3; ++s)
#pragma unroll
        for (int i = 0; i < 2; ++i)
#pragma unroll
            for (int p = 0; p < 8; ++p) acc[s][i][p] = (f4v){0.f, 0.f, 0.f, 0.f};

    int rA0 = wr + r15, rA1 = rA0 + 16;
    int gr0 = g * NPG + rA0; if (gr0 > NN - 1) gr0 = NN - 1;
    int gr1 = g * NPG + rA1; if (gr1 > NN - 1) gr1 = NN - 1;
    const u16* h0 = hb + (size_t)gr0 * 128 + gq * 8;
    const u16* h1 = hb + (size_t)gr1 * 128 + gq * 8;
    int dg0 = (rA0 < NPG) ? degL[rA0] : 0;
    int dg1 = (rA1 < NPG) ? degL[rA1] : 0;
    int rl0 = (rA0 < NPG) ? rlocL[rA0] : 0;
    int rl1 = (rA1 < NPG) ? rlocL[rA1] : 0;
    const u16* bbase = postB_l + (size_t)lane * 8;

#pragma unroll 1
    for (int ks = 0; ks < KS_POST; ++ks) {
        bf8v a0, a1;
        if (ks < 4) {
            a0 = *(const bf8v*)(h0 + ks * 32);
            a1 = *(const bf8v*)(h1 + ks * 32);
        } else {
            int f0 = ((ks - 4) * 32 + gq * 8) >> 2;
            a0 = vstat_frag(PsL, etL, epL, dg0, rl0, f0);
            a1 = vstat_frag(PsL, etL, epL, dg1, rl1, f0);
        }
        const u16* bk = bbase + (size_t)ks * 4096;
#pragma unroll
        for (int seg = 0; seg < 3; ++seg) {
            const u16* bs = bk + (size_t)seg * SEGB_SZ;
#pragma unroll
            for (int p = 0; p < 8; ++p) {
                bf8v bb = *(const bf8v*)(bs + p * 512);
                acc[seg][0][p] = __builtin_amdgcn_mfma_f32_16x16x32_bf16(a0, bb, acc[seg][0][p], 0, 0, 0);
                acc[seg][1][p] = __builtin_amdgcn_mfma_f32_16x16x32_bf16(a1, bb, acc[seg][1][p], 0, 0, 0);
            }
        }
    }
    // epilogue: out = acc0 + amp*acc1 + att*acc2 + bias (+ corr for deg==0 rows)
    int erow = wr + gq * 4;
#pragma unroll
    for (int fr = 0; fr < 2; ++fr) {
#pragma unroll
        for (int rr = 0; rr < 4; ++rr) {
            int row = erow + fr * 16 + rr;
            if (row >= NPG) continue;
            int dgr = degL[row];
            float cm = fmaxf((float)dgr, 1.f);
            float la = logf(cm + 1.f);
            float am = la / avgl, at = avgl / la;
            bool isz = (dgr == 0);
            size_t grow = (size_t)g * NPG + row;
#pragma unroll
            for (int p = 0; p < 8; ++p) {
                int col = r15 + p * 16;
                float val = acc[0][fr][p][rr] + am * acc[1][fr][p][rr] + at * acc[2][fr][p][rr];
                u16 ov = 0;
                if (col < F_) {
                    val += bias[col];
                    if (isz) val += b2f(corr[grow * 128 + col]);
                    ov = f2b(val);
                }
                outC[grow * 128 + col] = ov;
            }
        }
    }
}

// ---------------- BN apply + ReLU, vectorized short8 ----------------
__global__ void k_bn_apply(u16* __restrict__ hb, const float* __restrict__ sums,
                           const float* __restrict__ g, const float* __restrict__ b) {
    int idx = (blockIdx.x * 256 + threadIdx.x) * 8;
    if (idx >= NN * 128) return;
    int f0 = idx & 127;
    U4 u;
    u.v = *(const bf8v*)(hb + idx);
    float v[8];
#pragma unroll
    for (int i = 0; i < 4; ++i) { v[2 * i] = b2f_lo(u.a[i]); v[2 * i + 1] = b2f_hi(u.a[i]); }
    float o[8];
#pragma unroll
    for (int j = 0; j < 8; ++j) {
        int f = f0 + j;
        float r = 0.f;
        if (f < F_) {
            float mu  = sums[f] * (1.f / NN);
            float var = sums[128 + f] * (1.f / NN) - mu * mu;
            r = fmaxf(g[f] * (v[j] - mu) * rsqrtf(var + EPSV) + b[f], 0.f);
        }
        o[j] = r;
    }
    U4 w;
#pragma unroll
    for (int i = 0; i < 4; ++i) w.a[i] = (u32)f2b(o[2 * i]) | ((u32)f2b(o[2 * i + 1]) << 16);
    *(bf8v*)(hb + idx) = w.v;
}

// ---------------- pool (per-graph sum, vectorized) + 4-layer MLP head (fp32) --------------
__global__ __launch_bounds__(256) void k_pool_mlp(const u16* __restrict__ hb,
        const float* __restrict__ w1, const float* __restrict__ b1,
        const float* __restrict__ w2, const float* __restrict__ b2,
        const float* __restrict__ w3, const float* __restrict__ b3,
        const float* __restrict__ w4, const float* __restrict__ b4,
        float* __restrict__ out) {
    int gg = blockIdx.x;
    __shared__ float lsum[16][128];
    __shared__ float p[128];
    __shared__ float z1[100];
    __shared__ float z2[50];
    __shared__ float z3[25];
    int t = threadIdx.x;
    int cg = t & 15, rs = t >> 4;
    const u16* hbase = hb + (size_t)gg * NPG * 128 + cg * 8;
    float a8[8] = {};
    for (int r = rs; r < NPG; r += 16) {
        U4 u;
        u.v = *(const bf8v*)(hbase + (size_t)r * 128);
#pragma unroll
        for (int i = 0; i < 4; ++i) { a8[2 * i] += b2f_lo(u.a[i]); a8[2 * i + 1] += b2f_hi(u.a[i]); }
    }
#pragma unroll
    for (int j = 0; j < 8; ++j) lsum[rs][cg * 8 + j] = a8[j];
    __syncthreads();
    if (t < 128) {
        float s = 0.f;
#pragma unroll
        for (int k = 0; k < 16; ++k) s += lsum[k][t];
        p[t] = s;
    }
    __syncthreads();
    if (t < 100) {
        float s = b1[t];
        for (int c = 0; c < F_; ++c) s += p[c] * w1[c * 100 + t];
        z1[t] = fmaxf(s, 0.f);
    }
    __syncthreads();
    if (t < 50) {
        float s = b2[t];
        for (int c = 0; c < 100; ++c) s += z1[c] * w2[c * 50 + t];
        z2[t] = fmaxf(s, 0.f);
    }
    __syncthreads();
    if (t < 25) {
        float s = b3[t];
        for (int c = 0; c < 50; ++c) s += z2[c] * w3[c * 25 + t];
        z3[t] = fmaxf(s, 0.f);
    }
    __syncthreads();
    if (t == 0) {
        float s = b4[0];
        for (int c = 0; c < 25; ++c) s += z3[c] * w4[c];
        out[gg] = s;
    }
}

extern "C" void kernel_launch(void* const* d_in, const int* in_sizes, int n_in,
                              void* d_out, int out_size, void* d_ws, size_t ws_size,
                              hipStream_t stream) {
    const float* x        = (const float*)d_in[0];
    const int*   ei       = (const int*)d_in[1];
    const int*   src      = ei;
    const int*   dst      = ei + EE;
    const int*   eattr    = (const int*)d_in[2];
    const int*   deg_hist = (const int*)d_in[4];
    const float* emb1_w = (const float*)d_in[5];
    const float* emb1_b = (const float*)d_in[6];
    const float* edge_tab = (const float*)d_in[7];
    const float* enc_w  = (const float*)d_in[8];
    const float* enc_b  = (const float*)d_in[9];
    const float* pre_w  = (const float*)d_in[10];
    const float* pre_b  = (const float*)d_in[11];
    const float* post_w = (const float*)d_in[12];
    const float* post_b = (const float*)d_in[13];
    const float* lin_w  = (const float*)d_in[14];
    const float* lin_b  = (const float*)d_in[15];
    const float* bn_g   = (const float*)d_in[16];
    const float* bn_b   = (const float*)d_in[17];
    const float* w1 = (const float*)d_in[18];
    const float* b1 = (const float*)d_in[19];
    const float* w2 = (const float*)d_in[20];
    const float* b2 = (const float*)d_in[21];
    const float* w3 = (const float*)d_in[22];
    const float* b3 = (const float*)d_in[23];
    const float* w4 = (const float*)d_in[24];
    const float* b4 = (const float*)d_in[25];
    float* out = (float*)d_out;

    // ---- workspace layout (~105 MiB) ----
    char* base = (char*)d_ws;
    size_t o = 0;
    auto alloc = [&](size_t bytes) { char* r = base + o; o = (o + bytes + 255) & ~(size_t)255; return r; };
    u16*  hb    = (u16*)  alloc((size_t)NN * 128 * 2);
    u16*  Ps    = (u16*)  alloc((size_t)NN * 128 * 2);
    u16*  outA  = (u16*)  alloc((size_t)NN * 128 * 2);   // also the deg==0 corr buffer (alias)
    float* etab = (float*)alloc(4 * 10 * F_ * 4);
    float* Tbuf = (float*)alloc((size_t)12 * 128 * 128 * 4);
    float* WcBuf= (float*)alloc((size_t)4 * 128 * 128 * 4);
    float* bnsums = (float*)alloc(1024);
    int*  deg    = (int*)alloc((size_t)NN * 4);
    int*  rstart = (int*)alloc((size_t)NN * 4);
    int*  epack  = (int*)alloc((size_t)EE * 4);
    u16*  wjB   = (u16*)alloc((size_t)4 * SMALLB_SZ * 2);
    u16*  linB  = (u16*)alloc((size_t)4 * SMALLB_SZ * 2);
    u16*  wcB   = (u16*)alloc((size_t)4 * SMALLB_SZ * 2);
    u16*  postB = (u16*)alloc((size_t)12 * SEGB_SZ * 2);
    u16*  corr  = outA;

    // ---- setup ----
    k_embed<<<(NN * 128 / 8 + 255) / 256, 256, 0, stream>>>(x, emb1_w, emb1_b, hb);
    k_build_csr<<<G_, 128, 0, stream>>>(src, dst, eattr, deg, rstart, epack);
    k_build_etab<<<40, 128, 0, stream>>>(edge_tab, enc_w, enc_b, pre_w, pre_b, etab);
    k_fold_T<<<dim3(128, 12), 128, 0, stream>>>(pre_w, post_w, Tbuf);
    k_fold_Wc<<<(4 * 128 * 128 + 255) / 256, 256, 0, stream>>>(Tbuf, post_w, deg_hist, WcBuf);
    k_prep_B128<<<dim3(SMALLB_SZ / 256, 12), 256, 0, stream>>>(pre_w, lin_w, WcBuf, wjB, linB, wcB);
    k_prep_Bpost<<<dim3((SEGB_SZ + 255) / 256, 12), 256, 0, stream>>>(post_w, Tbuf, postB);

    for (int l = 0; l < 4; ++l) {
        hipMemsetAsync(bnsums, 0, 1024, stream);
        // Ps = h@Wj ; corr = h@Wc   (dual launch, bf16 out, zero pads)
        k_gemm_mfma<0, 0><<<dim3(NN / 64, 2), 256, 0, stream>>>(
            hb, wjB + (size_t)l * SMALLB_SZ, wcB + (size_t)l * SMALLB_SZ,
            nullptr, nullptr, Ps, corr, nullptr);
        // fused per-graph: vstat aggregation + 3-segment post GEMM + scalers
        k_post_fused<<<G_, 256, 0, stream>>>(
            hb, Ps, corr, etab + l * 10 * F_, deg, rstart, epack,
            postB + (size_t)(l * 3) * SEGB_SZ, post_b + l * F_, deg_hist, outA);
        // hb = outA @ lin_w + lin_b (in place) + fused BN stats
        k_gemm_mfma<0, 1><<<dim3(NN / 64, 1), 256, 0, stream>>>(
            outA, linB + (size_t)l * SMALLB_SZ, linB + (size_t)l * SMALLB_SZ,
            lin_b + l * F_, lin_b + l * F_, hb, hb, bnsums);
        k_bn_apply<<<(NN * 128 / 8 + 255) / 256, 256, 0, stream>>>(hb, bnsums,
                                                                   bn_g + l * F_, bn_b + l * F_);
    }

    k_pool_mlp<<<G_, 256, 0, stream>>>(hb, w1, b1, w2, b2, w3, b3, w4, b4, out);
}

// Round 9
// 1458.275 us; speedup vs baseline: 1.8040x; 1.8040x over previous
//
#include <hip/hip_runtime.h>
#include <math.h>

#define G_    1024
#define NPG   126
#define EPG   450
#define NN    (G_*NPG)      // 129024
#define EE    (G_*EPG)      // 460800
#define F_    126
#define EPSV  1e-5f
#define GCH   (G_/2)        // 512 graphs per chunk
#define CH    (NN/2)        // 64512 nodes per chunk

#define KS_POST 20                    // 4 (h, K=128) + 16 (vstat, K=512)
#define SEGB_SZ (KS_POST*8*64*8)      // 81920 shorts per (layer,seg)
#define SMALLB_SZ (4*8*64*8)          // 16384 shorts per 128x128 matrix

typedef unsigned short u16;
typedef unsigned int   u32;
typedef __attribute__((ext_vector_type(8))) short bf8v;   // 8 bf16 in 4 VGPRs
typedef __attribute__((ext_vector_type(4))) float f4v;

union U4 { bf8v v; u32 a[4]; };

__device__ __forceinline__ u16 f2b(float f) {              // RNE f32 -> bf16
    u32 u = __float_as_uint(f);
    u += 0x7FFFu + ((u >> 16) & 1u);
    return (u16)(u >> 16);
}
__device__ __forceinline__ float b2f(u16 s) { return __uint_as_float(((u32)s) << 16); }
__device__ __forceinline__ float b2f_lo(u32 u) { return __uint_as_float(u << 16); }
__device__ __forceinline__ float b2f_hi(u32 u) { return __uint_as_float(u & 0xFFFF0000u); }

// ---------------- node embedding: hb = bf16(x @ emb1_w + emb1_b), short8 stores ----------
__global__ void k_embed(const float* __restrict__ x, const float* __restrict__ w,
                        const float* __restrict__ b, u16* __restrict__ hb) {
    int idx = (blockIdx.x * 256 + threadIdx.x) * 8;
    if (idx >= NN * 128) return;
    int n = idx >> 7, f0 = idx & 127;
    float xr[5];
#pragma unroll
    for (int c = 0; c < 5; ++c) xr[c] = x[n * 5 + c];
    float v[8];
#pragma unroll
    for (int j = 0; j < 8; ++j) {
        int f = f0 + j;
        float s = 0.f;
        if (f < F_) {
            s = b[f];
#pragma unroll
            for (int c = 0; c < 5; ++c) s += xr[c] * w[c * F_ + f];
        }
        v[j] = s;
    }
    U4 o;
#pragma unroll
    for (int i = 0; i < 4; ++i) o.a[i] = (u32)f2b(v[2 * i]) | ((u32)f2b(v[2 * i + 1]) << 16);
    *(bf8v*)(hb + idx) = o.v;
}

// ---------------- per-graph CSR build: epack = src_local | attr<<8 ----------------
__global__ void k_build_csr(const int* __restrict__ src, const int* __restrict__ dst,
                            const int* __restrict__ attr,
                            int* __restrict__ deg, int* __restrict__ rstart,
                            int* __restrict__ epack) {
    int g = blockIdx.x;
    __shared__ int scnt[NPG];
    __shared__ int spos[NPG];
    int t = threadIdx.x;
    for (int j = t; j < NPG; j += blockDim.x) scnt[j] = 0;
    __syncthreads();
    int e0 = g * EPG;
    for (int i = t; i < EPG; i += blockDim.x) {
        int dl = dst[e0 + i] - g * NPG;
        atomicAdd(&scnt[dl], 1);
    }
    __syncthreads();
    if (t == 0) {
        int run = 0;
        for (int j = 0; j < NPG; ++j) { spos[j] = run; run += scnt[j]; }
    }
    __syncthreads();
    for (int j = t; j < NPG; j += blockDim.x) {
        deg[g * NPG + j]    = scnt[j];
        rstart[g * NPG + j] = e0 + spos[j];
    }
    __syncthreads();
    for (int j = t; j < NPG; j += blockDim.x) scnt[j] = 0;
    __syncthreads();
    for (int i = t; i < EPG; i += blockDim.x) {
        int e  = e0 + i;
        int dl = dst[e] - g * NPG;
        int p  = atomicAdd(&scnt[dl], 1);
        epack[e0 + spos[dl] + p] = (src[e] - g * NPG) | (attr[e] << 8);  // local src <126
    }
}

// ---------------- per-node degree scalers ----------------
__global__ void k_node_scalars(const int* __restrict__ deg, const int* __restrict__ deg_hist,
                               float* __restrict__ ampv, float* __restrict__ attv) {
    int n = blockIdx.x * blockDim.x + threadIdx.x;
    if (n >= NN) return;
    float sum = 0.f, sl = 0.f;
#pragma unroll
    for (int b = 0; b < 5; ++b) {
        float dh = (float)deg_hist[b];
        sum += dh;
        sl  += dh * logf((float)b + 1.f);
    }
    float avg_log = sl / sum;
    float cm = fmaxf((float)deg[n], 1.f);
    float la = logf(cm + 1.f);
    ampv[n] = la / avg_log;
    attv[n] = avg_log / la;
}

// ---------------- edge-attr table (fp32): etab[(l*10+a)*F_ + f] ----------------
__global__ void k_build_etab(const float* __restrict__ edge_tab, const float* __restrict__ enc_w,
                             const float* __restrict__ enc_b, const float* __restrict__ pre_w,
                             const float* __restrict__ pre_b, float* __restrict__ etab) {
    int l = blockIdx.x / 10, a = blockIdx.x % 10;
    __shared__ float tmp[F_];
    int t = threadIdx.x;
    if (t < F_) {
        float s = enc_b[l * F_ + t];
        for (int c = 0; c < 50; ++c) s += edge_tab[a * 50 + c] * enc_w[(l * 50 + c) * F_ + t];
        tmp[t] = s;
    }
    __syncthreads();
    if (t < F_) {
        float s = pre_b[l * F_ + t];
        for (int j = 0; j < F_; ++j) s += tmp[j] * pre_w[((size_t)l * 378 + 252 + j) * F_ + t];
        etab[(l * 10 + a) * F_ + t] = s;
    }
}

// ------------- fold: T[l][seg][k][c] = (seg==0? B0 : 0) + sum_f Wi[k][f]*Bsum_seg[f][c] -----
__global__ void k_fold_T(const float* __restrict__ pre_w, const float* __restrict__ post_w,
                         float* __restrict__ Tbuf) {
    int k = blockIdx.x;                 // 0..127
    int y = blockIdx.y;                 // l*3+seg
    int l = y / 3, seg = y % 3;
    int c = threadIdx.x;                // 0..127
    __shared__ float wi[128];
    wi[c] = (k < F_ && c < F_) ? pre_w[((size_t)l * 378 + k) * F_ + c] : 0.f;
    __syncthreads();
    float s = 0.f;
    if (k < F_ && c < F_) {
        const float* pw = post_w + (size_t)l * 1638 * F_;
        if (seg == 0) s = pw[(size_t)k * F_ + c];
        int base = 126 + seg * 504;
        for (int f = 0; f < F_; ++f) {
            float bs = pw[(size_t)(base + f) * F_ + c]
                     + pw[(size_t)(base + 126 + f) * F_ + c]
                     + pw[(size_t)(base + 252 + f) * F_ + c];
            s += wi[f] * bs;
        }
    }
    Tbuf[((size_t)y * 128 + k) * 128 + c] = s;
}

// ------------- Wc[l][k][c] = -((T1-B0) + amp0*T2 + att0*T3)  (deg==0 correction weights) ----
__global__ void k_fold_Wc(const float* __restrict__ Tbuf, const float* __restrict__ post_w,
                          const int* __restrict__ deg_hist, float* __restrict__ WcBuf) {
    int idx = blockIdx.x * 256 + threadIdx.x;
    if (idx >= 4 * 128 * 128) return;
    int l = idx >> 14, k = (idx >> 7) & 127, c = idx & 127;
    float dsum = 0.f, dsl = 0.f;
#pragma unroll
    for (int b = 0; b < 5; ++b) {
        float dh = (float)deg_hist[b];
        dsum += dh; dsl += dh * logf((float)b + 1.f);
    }
    float avgl = dsl / dsum;
    float l2 = logf(2.f);
    float amp0 = l2 / avgl, att0 = avgl / l2;
    float t1 = Tbuf[((size_t)(l * 3 + 0) * 128 + k) * 128 + c];
    float t2 = Tbuf[((size_t)(l * 3 + 1) * 128 + k) * 128 + c];
    float t3 = Tbuf[((size_t)(l * 3 + 2) * 128 + k) * 128 + c];
    float b0 = (k < F_ && c < F_) ? post_w[((size_t)l * 1638 + k) * F_ + c] : 0.f;
    WcBuf[((size_t)l * 128 + k) * 128 + c] = -((t1 - b0) + amp0 * t2 + att0 * t3);
}

// ---------------- B prep (128x128): frag-linear bf16 ----------------
__global__ void k_prep_B128(const float* __restrict__ pre_w, const float* __restrict__ lin_w,
                            const float* __restrict__ WcBuf,
                            u16* __restrict__ wjB, u16* __restrict__ linB,
                            u16* __restrict__ wcB) {
    int idx = blockIdx.x * 256 + threadIdx.x;        // 0..16383
    int y = blockIdx.y;                              // 0..11
    int l = y & 3, ty = y >> 2;
    int j = idx & 7, lane = (idx >> 3) & 63, pnl = (idx >> 9) & 7, ks = idx >> 12;
    int k = ks * 32 + (lane >> 4) * 8 + j;
    int c = pnl * 16 + (lane & 15);
    float v;
    if (ty == 2) {
        v = WcBuf[((size_t)l * 128 + k) * 128 + c];
    } else {
        const float* W = (ty == 0) ? pre_w + ((size_t)l * 378 + 126) * F_
                                   : lin_w + (size_t)l * F_ * F_;
        v = (k < F_ && c < F_) ? W[(size_t)k * F_ + c] : 0.f;
    }
    u16* out = ((ty == 0) ? wjB : (ty == 1) ? linB : wcB) + (size_t)l * SMALLB_SZ;
    out[idx] = f2b(v);
}

// post B per (l,seg): ks<4 -> T rows; ks>=4 -> interleaved vstat rows a=f*4+t
__global__ void k_prep_Bpost(const float* __restrict__ post_w, const float* __restrict__ Tbuf,
                             u16* __restrict__ postB) {
    int idx = blockIdx.x * 256 + threadIdx.x;
    if (idx >= SEGB_SZ) return;
    int y = blockIdx.y;                 // l*3+seg
    int l = y / 3, seg = y % 3;
    int j = idx & 7, lane = (idx >> 3) & 63, pnl = (idx >> 9) & 7, ks = idx >> 12;
    int c  = pnl * 16 + (lane & 15);
    int kk = (lane >> 4) * 8 + j;       // 0..31
    float val = 0.f;
    if (ks < 4) {
        int k = ks * 32 + kk;           // 0..127 (T zero-padded)
        val = Tbuf[((size_t)y * 128 + k) * 128 + c];
    } else {
        int kv = (ks - 4) * 32 + kk;    // 0..511
        int f = kv >> 2, t = kv & 3;    // t: 0 mean, 1 min, 2 max, 3 std
        if (f < F_ && c < F_)
            val = post_w[((size_t)l * 1638 + 126 + seg * 504 + t * 126 + f) * F_ + c];
    }
    postB[(size_t)y * SEGB_SZ + idx] = f2b(val);
}

// ---------------- small MFMA GEMM (K=128), dual via grid.y, optional fused BN stats --------
template<int OF32, int BNSTAT>
__global__ __launch_bounds__(256) void k_gemm_mfma(
        const u16* __restrict__ A0,
        const u16* __restrict__ Bv0, const u16* __restrict__ Bv1,
        const float* __restrict__ bias0, const float* __restrict__ bias1,
        void* __restrict__ C0, void* __restrict__ C1,
        float* __restrict__ bns) {
    const u16* Bv = blockIdx.y ? Bv1 : Bv0;
    const float* bias = blockIdx.y ? bias1 : bias0;
    void* C = blockIdx.y ? C1 : C0;
    __shared__ float ldsS[128];
    __shared__ float ldsQ[128];
    int tid = threadIdx.x;
    if (BNSTAT) {
        if (tid < 128) { ldsS[tid] = 0.f; ldsQ[tid] = 0.f; }
        __syncthreads();
    }
    int lane = tid & 63, wid = tid >> 6;
    int g = lane >> 4, r15 = lane & 15;
    int wr = (wid >> 1) * 32, wc = (wid & 1) * 64;
    size_t row0 = (size_t)blockIdx.x * 64 + wr + r15;
    const u16* a0p = A0 + row0 * 128 + g * 8;
    const u16* a1p = a0p + 16 * 128;
    const u16* bp = Bv + ((size_t)(wc >> 4) * 64 + lane) * 8;
    f4v acc[2][4];
#pragma unroll
    for (int i = 0; i < 2; ++i)
#pragma unroll
        for (int j = 0; j < 4; ++j) acc[i][j] = (f4v){0.f, 0.f, 0.f, 0.f};

#pragma unroll
    for (int ks = 0; ks < 4; ++ks) {
        bf8v a0 = *(const bf8v*)(a0p + ks * 32);
        bf8v a1 = *(const bf8v*)(a1p + ks * 32);
        const u16* bk = bp + (size_t)ks * 4096;
#pragma unroll
        for (int fc = 0; fc < 4; ++fc) {
            bf8v bb = *(const bf8v*)(bk + fc * 512);
            acc[0][fc] = __builtin_amdgcn_mfma_f32_16x16x32_bf16(a0, bb, acc[0][fc], 0, 0, 0);
            acc[1][fc] = __builtin_amdgcn_mfma_f32_16x16x32_bf16(a1, bb, acc[1][fc], 0, 0, 0);
        }
    }
    int erow = blockIdx.x * 64 + wr + g * 4;
    int ecol = wc + r15;
#pragma unroll
    for (int fc = 0; fc < 4; ++fc) {
        int col = ecol + fc * 16;
        float bv = (bias && col < F_) ? bias[col] : 0.f;
        float s = 0.f, q = 0.f;
#pragma unroll
        for (int fr = 0; fr < 2; ++fr) {
#pragma unroll
            for (int r = 0; r < 4; ++r) {
                int row = erow + fr * 16 + r;
                float val = acc[fr][fc][r] + bv;
                if (BNSTAT) { s += val; q += val * val; }
                if (OF32) {
                    if (col < F_) ((float*)C)[(size_t)row * 128 + col] = val;
                } else {
                    ((u16*)C)[(size_t)row * 128 + col] = (col < F_) ? f2b(val) : (u16)0;
                }
            }
        }
        if (BNSTAT) { atomicAdd(&ldsS[col], s); atomicAdd(&ldsQ[col], q); }
    }
    if (BNSTAT) {
        __syncthreads();
        if (tid < 128) {
            atomicAdd(&bns[tid], ldsS[tid]);
            atomicAdd(&bns[128 + tid], ldsQ[tid]);
        }
    }
}

// ---------------- wave-uniform per-graph aggregation -> aggb[node][512] bf16 ----------------
// lane = feature-pair (2 features), wave = node: dg loop uniform across the wave.
__global__ __launch_bounds__(256) void k_agg2(
        const u16* __restrict__ Psc,       // Ps chunk base [GCH*NPG][128]
        const float* __restrict__ etab_l,
        const int* __restrict__ deg, const int* __restrict__ rstart,
        const int* __restrict__ epack,
        u16* __restrict__ aggc, int g0) {
    __shared__ u32  PsL[126 * 65];         // pad 65: conflict-free
    __shared__ float etLo[10 * 64];
    __shared__ float etHi[10 * 64];
    __shared__ u32  epL[EPG];
    __shared__ int  degL[NPG];
    __shared__ int  rlL[NPG];
    int gg = g0 + blockIdx.x;              // global graph
    int tid = threadIdx.x;
    const u16* psrow = Psc + (size_t)blockIdx.x * NPG * 128;
    for (int i = tid; i < NPG * 16; i += 256) {
        int r = i >> 4, q = i & 15;
        U4 u; u.v = *(const bf8v*)(psrow + (size_t)r * 128 + q * 8);
        u32* dp = &PsL[r * 65 + q * 4];
        dp[0] = u.a[0]; dp[1] = u.a[1]; dp[2] = u.a[2]; dp[3] = u.a[3];
    }
    for (int i = tid; i < 640; i += 256) {
        int a = i >> 6, ln = i & 63;
        int f = 2 * ln;
        etLo[i] = (f < F_) ? etab_l[a * F_ + f] : 0.f;
        etHi[i] = (f + 1 < F_) ? etab_l[a * F_ + f + 1] : 0.f;
    }
    for (int e = tid; e < EPG; e += 256) epL[e] = (u32)epack[(size_t)gg * EPG + e];
    if (tid < NPG) {
        degL[tid] = deg[(size_t)gg * NPG + tid];
        rlL[tid]  = rstart[(size_t)gg * NPG + tid] - gg * EPG;
    }
    __syncthreads();

    int lane = tid & 63, wid = tid >> 6;
    for (int nd = wid; nd < NPG; nd += 4) {
        int dg = degL[nd], rl = rlL[nd];
        float s0 = 0.f, q0 = 0.f, s1 = 0.f, q1 = 0.f;
        float n0 = 3.4e38f, x0 = -3.4e38f, n1 = 3.4e38f, x1 = -3.4e38f;
        for (int e = 0; e < dg; ++e) {
            u32 pk = epL[rl + e];                // broadcast (uniform)
            int sN = pk & 255, at = pk >> 8;
            u32 pv = PsL[sN * 65 + lane];
            float v0 = b2f_lo(pv) + etLo[at * 64 + lane];
            float v1 = b2f_hi(pv) + etHi[at * 64 + lane];
            s0 += v0; q0 += v0 * v0; n0 = fminf(n0, v0); x0 = fmaxf(x0, v0);
            s1 += v1; q1 += v1 * v1; n1 = fminf(n1, v1); x1 = fmaxf(x1, v1);
        }
        float m0, m1, d0, d1;
        if (dg == 0) {
            m0 = m1 = 0.f; n0 = x0 = n1 = x1 = 0.f;
            d0 = d1 = 0.0031622776601683794f;    // sqrt(1e-5)
        } else {
            float ic = 1.f / (float)dg;
            m0 = s0 * ic; m1 = s1 * ic;
            d0 = sqrtf(fmaxf(q0 * ic - m0 * m0, 0.f) + EPSV);
            d1 = sqrtf(fmaxf(q1 * ic - m1 * m1, 0.f) + EPSV);
        }
        U4 o;
        o.a[0] = (u32)f2b(m0) | ((u32)f2b(n0) << 16);
        o.a[1] = (u32)f2b(x0) | ((u32)f2b(d0) << 16);
        o.a[2] = (u32)f2b(m1) | ((u32)f2b(n1) << 16);
        o.a[3] = (u32)f2b(x1) | ((u32)f2b(d1) << 16);
        *(bf8v*)(aggc + ((size_t)blockIdx.x * NPG + nd) * 512 + lane * 8) = o.v;
    }
}

// ---------------- post GEMM: out = [h|vstat]@(T1;B1) + amp*(..2) + att*(..3) + bias (+corr) --
__global__ __launch_bounds__(256) void k_post2(
        const u16* __restrict__ hA, const u16* __restrict__ aggc,
        const u16* __restrict__ corr,
        const float* __restrict__ ampc, const float* __restrict__ attc,
        const int* __restrict__ degc,
        const u16* __restrict__ postB_l, const float* __restrict__ bias,
        u16* __restrict__ outC) {
    int lane = threadIdx.x & 63, wid = threadIdx.x >> 6;
    int gq = lane >> 4, r15 = lane & 15;
    int wr = (wid >> 1) * 32, wc = (wid & 1) * 64;
    size_t row0 = (size_t)blockIdx.x * 64 + wr + r15;
    const u16* h0 = hA + row0 * 128 + gq * 8;
    const u16* h1 = h0 + 16 * 128;
    const u16* g0p = aggc + row0 * 512 + gq * 8;
    const u16* g1p = g0p + 16 * 512;
    const u16* bp = postB_l + ((size_t)(wc >> 4) * 64 + lane) * 8;
    f4v acc[3][2][4];
#pragma unroll
    for (int s = 0; s < 3; ++s)
#pragma unroll
        for (int i = 0; i < 2; ++i)
#pragma unroll
            for (int j = 0; j < 4; ++j) acc[s][i][j] = (f4v){0.f, 0.f, 0.f, 0.f};

#pragma unroll
    for (int ks = 0; ks < 4; ++ks) {
        bf8v a0 = *(const bf8v*)(h0 + ks * 32);
        bf8v a1 = *(const bf8v*)(h1 + ks * 32);
        const u16* bk = bp + (size_t)ks * 4096;
#pragma unroll
        for (int seg = 0; seg < 3; ++seg) {
            const u16* bs = bk + (size_t)seg * SEGB_SZ;
#pragma unroll
            for (int fc = 0; fc < 4; ++fc) {
                bf8v bb = *(const bf8v*)(bs + fc * 512);
                acc[seg][0][fc] = __builtin_amdgcn_mfma_f32_16x16x32_bf16(a0, bb, acc[seg][0][fc], 0, 0, 0);
                acc[seg][1][fc] = __builtin_amdgcn_mfma_f32_16x16x32_bf16(a1, bb, acc[seg][1][fc], 0, 0, 0);
            }
        }
    }
#pragma unroll 2
    for (int ks = 0; ks < 16; ++ks) {
        bf8v a0 = *(const bf8v*)(g0p + ks * 32);
        bf8v a1 = *(const bf8v*)(g1p + ks * 32);
        const u16* bk = bp + (size_t)(4 + ks) * 4096;
#pragma unroll
        for (int seg = 0; seg < 3; ++seg) {
            const u16* bs = bk + (size_t)seg * SEGB_SZ;
#pragma unroll
            for (int fc = 0; fc < 4; ++fc) {
                bf8v bb = *(const bf8v*)(bs + fc * 512);
                acc[seg][0][fc] = __builtin_amdgcn_mfma_f32_16x16x32_bf16(a0, bb, acc[seg][0][fc], 0, 0, 0);
                acc[seg][1][fc] = __builtin_amdgcn_mfma_f32_16x16x32_bf16(a1, bb, acc[seg][1][fc], 0, 0, 0);
            }
        }
    }
    int erow = blockIdx.x * 64 + wr + gq * 4;
    int ecol = wc + r15;
#pragma unroll
    for (int fr = 0; fr < 2; ++fr) {
#pragma unroll
        for (int rr = 0; rr < 4; ++rr) {
            int row = erow + fr * 16 + rr;
            float am = ampc[row], at = attc[row];
            bool isz = (degc[row] == 0);
#pragma unroll
            for (int fc = 0; fc < 4; ++fc) {
                int col = ecol + fc * 16;
                float val = acc[0][fr][fc][rr] + am * acc[1][fr][fc][rr]
                          + at * acc[2][fr][fc][rr];
                u16 ov = 0;
                if (col < F_) {
                    val += bias[col];
                    if (isz) val += b2f(corr[(size_t)row * 128 + col]);
                    ov = f2b(val);
                }
                outC[(size_t)row * 128 + col] = ov;
            }
        }
    }
}

// ---------------- BN apply + ReLU, vectorized short8 ----------------
__global__ void k_bn_apply(u16* __restrict__ hb, const float* __restrict__ sums,
                           const float* __restrict__ g, const float* __restrict__ b) {
    int idx = (blockIdx.x * 256 + threadIdx.x) * 8;
    if (idx >= NN * 128) return;
    int f0 = idx & 127;
    U4 u;
    u.v = *(const bf8v*)(hb + idx);
    float v[8];
#pragma unroll
    for (int i = 0; i < 4; ++i) { v[2 * i] = b2f_lo(u.a[i]); v[2 * i + 1] = b2f_hi(u.a[i]); }
    float o[8];
#pragma unroll
    for (int j = 0; j < 8; ++j) {
        int f = f0 + j;
        float r = 0.f;
        if (f < F_) {
            float mu  = sums[f] * (1.f / NN);
            float var = sums[128 + f] * (1.f / NN) - mu * mu;
            r = fmaxf(g[f] * (v[j] - mu) * rsqrtf(var + EPSV) + b[f], 0.f);
        }
        o[j] = r;
    }
    U4 w;
#pragma unroll
    for (int i = 0; i < 4; ++i) w.a[i] = (u32)f2b(o[2 * i]) | ((u32)f2b(o[2 * i + 1]) << 16);
    *(bf8v*)(hb + idx) = w.v;
}

// ---------------- pool (per-graph sum, vectorized) + 4-layer MLP head (fp32) --------------
__global__ __launch_bounds__(256) void k_pool_mlp(const u16* __restrict__ hb,
        const float* __restrict__ w1, const float* __restrict__ b1,
        const float* __restrict__ w2, const float* __restrict__ b2,
        const float* __restrict__ w3, const float* __restrict__ b3,
        const float* __restrict__ w4, const float* __restrict__ b4,
        float* __restrict__ out) {
    int gg = blockIdx.x;
    __shared__ float lsum[16][128];
    __shared__ float p[128];
    __shared__ float z1[100];
    __shared__ float z2[50];
    __shared__ float z3[25];
    int t = threadIdx.x;
    int cg = t & 15, rs = t >> 4;
    const u16* hbase = hb + (size_t)gg * NPG * 128 + cg * 8;
    float a8[8] = {};
    for (int r = rs; r < NPG; r += 16) {
        U4 u;
        u.v = *(const bf8v*)(hbase + (size_t)r * 128);
#pragma unroll
        for (int i = 0; i < 4; ++i) { a8[2 * i] += b2f_lo(u.a[i]); a8[2 * i + 1] += b2f_hi(u.a[i]); }
    }
#pragma unroll
    for (int j = 0; j < 8; ++j) lsum[rs][cg * 8 + j] = a8[j];
    __syncthreads();
    if (t < 128) {
        float s = 0.f;
#pragma unroll
        for (int k = 0; k < 16; ++k) s += lsum[k][t];
        p[t] = s;
    }
    __syncthreads();
    if (t < 100) {
        float s = b1[t];
        for (int c = 0; c < F_; ++c) s += p[c] * w1[c * 100 + t];
        z1[t] = fmaxf(s, 0.f);
    }
    __syncthreads();
    if (t < 50) {
        float s = b2[t];
        for (int c = 0; c < 100; ++c) s += z1[c] * w2[c * 50 + t];
        z2[t] = fmaxf(s, 0.f);
    }
    __syncthreads();
    if (t < 25) {
        float s = b3[t];
        for (int c = 0; c < 50; ++c) s += z2[c] * w3[c * 25 + t];
        z3[t] = fmaxf(s, 0.f);
    }
    __syncthreads();
    if (t == 0) {
        float s = b4[0];
        for (int c = 0; c < 25; ++c) s += z3[c] * w4[c];
        out[gg] = s;
    }
}

extern "C" void kernel_launch(void* const* d_in, const int* in_sizes, int n_in,
                              void* d_out, int out_size, void* d_ws, size_t ws_size,
                              hipStream_t stream) {
    const float* x        = (const float*)d_in[0];
    const int*   ei       = (const int*)d_in[1];
    const int*   src      = ei;
    const int*   dst      = ei + EE;
    const int*   eattr    = (const int*)d_in[2];
    const int*   deg_hist = (const int*)d_in[4];
    const float* emb1_w = (const float*)d_in[5];
    const float* emb1_b = (const float*)d_in[6];
    const float* edge_tab = (const float*)d_in[7];
    const float* enc_w  = (const float*)d_in[8];
    const float* enc_b  = (const float*)d_in[9];
    const float* pre_w  = (const float*)d_in[10];
    const float* pre_b  = (const float*)d_in[11];
    const float* post_w = (const float*)d_in[12];
    const float* post_b = (const float*)d_in[13];
    const float* lin_w  = (const float*)d_in[14];
    const float* lin_b  = (const float*)d_in[15];
    const float* bn_g   = (const float*)d_in[16];
    const float* bn_b   = (const float*)d_in[17];
    const float* w1 = (const float*)d_in[18];
    const float* b1 = (const float*)d_in[19];
    const float* w2 = (const float*)d_in[20];
    const float* b2 = (const float*)d_in[21];
    const float* w3 = (const float*)d_in[22];
    const float* b3 = (const float*)d_in[23];
    const float* w4 = (const float*)d_in[24];
    const float* b4 = (const float*)d_in[25];
    float* out = (float*)d_out;

    // ---- workspace layout (~172 MiB) ----
    char* base = (char*)d_ws;
    size_t o = 0;
    auto alloc = [&](size_t bytes) { char* r = base + o; o = (o + bytes + 255) & ~(size_t)255; return r; };
    u16*  hb    = (u16*)  alloc((size_t)NN * 128 * 2);
    u16*  Ps    = (u16*)  alloc((size_t)NN * 128 * 2);
    u16*  outA  = (u16*)  alloc((size_t)NN * 128 * 2);   // also the deg==0 corr buffer (alias)
    u16*  aggb  = (u16*)  alloc((size_t)CH * 512 * 2);   // per-chunk vstat buffer
    float* etab = (float*)alloc(4 * 10 * F_ * 4);
    float* Tbuf = (float*)alloc((size_t)12 * 128 * 128 * 4);
    float* WcBuf= (float*)alloc((size_t)4 * 128 * 128 * 4);
    float* ampv = (float*)alloc((size_t)NN * 4);
    float* attv = (float*)alloc((size_t)NN * 4);
    float* bnsums = (float*)alloc(1024);
    int*  deg    = (int*)alloc((size_t)NN * 4);
    int*  rstart = (int*)alloc((size_t)NN * 4);
    int*  epack  = (int*)alloc((size_t)EE * 4);
    u16*  wjB   = (u16*)alloc((size_t)4 * SMALLB_SZ * 2);
    u16*  linB  = (u16*)alloc((size_t)4 * SMALLB_SZ * 2);
    u16*  wcB   = (u16*)alloc((size_t)4 * SMALLB_SZ * 2);
    u16*  postB = (u16*)alloc((size_t)12 * SEGB_SZ * 2);
    u16*  corr  = outA;

    // ---- setup ----
    k_embed<<<(NN * 128 / 8 + 255) / 256, 256, 0, stream>>>(x, emb1_w, emb1_b, hb);
    k_build_csr<<<G_, 128, 0, stream>>>(src, dst, eattr, deg, rstart, epack);
    k_node_scalars<<<(NN + 255) / 256, 256, 0, stream>>>(deg, deg_hist, ampv, attv);
    k_build_etab<<<40, 128, 0, stream>>>(edge_tab, enc_w, enc_b, pre_w, pre_b, etab);
    k_fold_T<<<dim3(128, 12), 128, 0, stream>>>(pre_w, post_w, Tbuf);
    k_fold_Wc<<<(4 * 128 * 128 + 255) / 256, 256, 0, stream>>>(Tbuf, post_w, deg_hist, WcBuf);
    k_prep_B128<<<dim3(SMALLB_SZ / 256, 12), 256, 0, stream>>>(pre_w, lin_w, WcBuf, wjB, linB, wcB);
    k_prep_Bpost<<<dim3((SEGB_SZ + 255) / 256, 12), 256, 0, stream>>>(post_w, Tbuf, postB);

    for (int l = 0; l < 4; ++l) {
        hipMemsetAsync(bnsums, 0, 1024, stream);
        // Ps = h@Wj ; corr = h@Wc   (dual launch, bf16 out, zero pads)
        k_gemm_mfma<0, 0><<<dim3(NN / 64, 2), 256, 0, stream>>>(
            hb, wjB + (size_t)l * SMALLB_SZ, wcB + (size_t)l * SMALLB_SZ,
            nullptr, nullptr, Ps, corr, nullptr);
        for (int c = 0; c < 2; ++c) {
            int g0 = c * GCH;
            size_t r0 = (size_t)g0 * NPG;
            k_agg2<<<GCH, 256, 0, stream>>>(Ps + r0 * 128, etab + l * 10 * F_,
                                            deg, rstart, epack, aggb, g0);
            k_post2<<<CH / 64, 256, 0, stream>>>(
                hb + r0 * 128, aggb, corr + r0 * 128,
                ampv + r0, attv + r0, deg + r0,
                postB + (size_t)(l * 3) * SEGB_SZ, post_b + l * F_, outA + r0 * 128);
        }
        // hb = outA @ lin_w + lin_b (in place) + fused BN stats
        k_gemm_mfma<0, 1><<<dim3(NN / 64, 1), 256, 0, stream>>>(
            outA, linB + (size_t)l * SMALLB_SZ, linB + (size_t)l * SMALLB_SZ,
            lin_b + l * F_, lin_b + l * F_, hb, hb, bnsums);
        k_bn_apply<<<(NN * 128 / 8 + 255) / 256, 256, 0, stream>>>(hb, bnsums,
                                                                   bn_g + l * F_, bn_b + l * F_);
    }

    k_pool_mlp<<<G_, 256, 0, stream>>>(hb, w1, b1, w2, b2, w3, b3, w4, b4, out);
}